// Round 7
// baseline (714.033 us; speedup 1.0000x reference)
//
#include <hip/hip_runtime.h>

typedef _Float16 f16;
typedef _Float16 f16x8 __attribute__((ext_vector_type(8)));
typedef _Float16 f16x4 __attribute__((ext_vector_type(4)));
typedef float floatx4 __attribute__((ext_vector_type(4)));

#define TPI 6.283185307179586f
#define WSCALE 256.0f
#define INV_WSCALE (1.0f / 256.0f)

// async global->LDS, 16B per lane; LDS dest = wave-uniform base + lane*16
__device__ __forceinline__ void llds16(const f16* g, f16* l)
{
    __builtin_amdgcn_global_load_lds(
        (const __attribute__((address_space(1))) unsigned int*)g,
        (__attribute__((address_space(3))) unsigned int*)l, 16, 0, 0);
}

// ---------------- prep: Xh half (8192 rows) fp32 -> f16, K-pad 720->768 -------
__global__ void prep_xh(const float* __restrict__ x, f16* __restrict__ Xh)
{
    const int TT = 8192 * 96;          // f16x8 groups
    for (int i = blockIdx.x * 256 + threadIdx.x; i < TT; i += gridDim.x * 256) {
        int r = i / 96, g = (i - r * 96) * 8;
        f16x8 o = {};
        if (g < 720) {
            const float* xp = x + (size_t)r * 720 + g;
            float4 v0 = *(const float4*)xp;
            float4 v1 = *(const float4*)(xp + 4);
            o = (f16x8){(f16)v0.x, (f16)v0.y, (f16)v0.z, (f16)v0.w,
                        (f16)v1.x, (f16)v1.y, (f16)v1.z, (f16)v1.w};
        }
        *(f16x8*)(Xh + (size_t)r * 768 + g) = o;
    }
}

// ---------------- prep: weights (B2 packed split planes x256) + small mats ----
__global__ void prep_w(const float* __restrict__ w1, const float* __restrict__ w2,
                       const float* __restrict__ dw1, const float* __restrict__ dw2,
                       f16* __restrict__ B2,
                       f16* __restrict__ W2h, f16* __restrict__ W2l,
                       f16* __restrict__ D1, f16* __restrict__ D2)
{
    const int T1 = 3712 * 768;   // W1 im2col [n=o*15+t][k=c*15+s] -> B2 [n][bh|bl]
    const int T2 = 96 * 3648;    // W2 [n=e*15+t][k=m*15+s] -> planes
    const int T3 = 3712 * 96;    // D1 [n=m*15+t][k=e*15+s]
    const int T4 = 48 * 3648;    // D2 [o][k=m*15+s], s>=7 (last output position)
    const int TT = T1 + T2 + T3 + T4;
    for (int i = blockIdx.x * 256 + threadIdx.x; i < TT; i += gridDim.x * 256) {
        if (i < T1) {
            int n = i / 768, k = i - n * 768;
            float v = 0.f;
            if (n < 3600 && k < 720) {
                int o = n / 15, t = n - o * 15, c = k / 15, s = k - c * 15, d = s - t + 7;
                if (d >= 0 && d < 15) v = w1[(o * 48 + c) * 15 + d];
            }
            v *= WSCALE;
            f16 hi = (f16)v;
            f16* row = B2 + (size_t)n * 1536 + k;
            row[0] = hi;
            row[768] = (f16)(v - (float)hi);
        } else if (i < T1 + T2) {
            int j = i - T1;
            int n = j / 3648, k = j - n * 3648;
            float v = 0.f;
            if (n < 90 && k < 3600) {
                int e = n / 15, t = n - e * 15, m = k / 15, s = k - m * 15, d = s - t + 7;
                if (d >= 0 && d < 15) v = w2[(e * 240 + m) * 15 + d];
            }
            v *= WSCALE;
            f16 hi = (f16)v;
            W2h[j] = hi; W2l[j] = (f16)(v - (float)hi);
        } else if (i < T1 + T2 + T3) {
            int j = i - T1 - T2;
            int n = j / 96, k = j - n * 96;
            float v = 0.f;
            if (n < 3600 && k < 90) {
                int m = n / 15, t = n - m * 15, e = k / 15, s = k - e * 15, d = s - t + 7;
                if (d >= 0 && d < 15) v = dw1[(m * 6 + e) * 15 + d];
            }
            D1[j] = (f16)v;
        } else {
            int j = i - T1 - T2 - T3;
            int o = j / 3648, k = j - o * 3648;
            float v = 0.f;
            if (k < 3600) {
                int m = k / 15, s = k - m * 15;
                if (s >= 7) v = dw2[(o * 240 + m) * 15 + (s - 7)];
            }
            D2[j] = (f16)v;
        }
    }
}

// ---------------- conv1: 2-term split GEMM, fully-async staging ---------------
// Xh [8192][768] f16 (local rows); B2 [3712][1536] f16 (x256, bh|bl).
// H1 [16384][3600] fp32 (global rows m0+...) + stats. LDS-repacked C store.
__global__ __launch_bounds__(256, 3) void gemm1_async(
    const f16* __restrict__ Xh, const f16* __restrict__ B2,
    float* __restrict__ H1, const float* __restrict__ bias,
    float* __restrict__ ssum, float* __restrict__ ssq, int m0)
{
    const int tid = threadIdx.x;
    const int wave = tid >> 6, lane = tid & 63;
    const int l15 = lane & 15, q = lane >> 4;
    const int wm = wave >> 1, wn = wave & 1;
    const int bm = blockIdx.x * 128, bn = blockIdx.y * 128;

    __shared__ __align__(16) char smem[49152];
    f16* Asw  = (f16*)smem;                 // 128*64 swizzled
    f16* Bsw0 = (f16*)(smem + 16384);       // bh plane
    f16* Bsw1 = (f16*)(smem + 32768);       // bl plane
    float (*Cf)[132] = (float(*)[132])smem; // repack buffer (64 rows), aliases staging

    floatx4 acc[4][4];
#pragma unroll
    for (int i = 0; i < 4; i++)
#pragma unroll
        for (int j = 0; j < 4; j++) acc[i][j] = (floatx4){0.f, 0.f, 0.f, 0.f};

    for (int kt = 0; kt < 12; kt++) {
        const int k0 = kt * 64;
#pragma unroll
        for (int it = 0; it < 4; it++) {
            int c = it * 256 + tid;                    // 1024 chunks/plane
            int row = c >> 3;
            int seg = (c & 7) ^ (row & 7);
            llds16(Xh + (size_t)(bm + row) * 768 + k0 + seg * 8, Asw + (size_t)c * 8);
            const f16* gb = B2 + (size_t)(bn + row) * 1536 + k0 + seg * 8;
            llds16(gb,       Bsw0 + (size_t)c * 8);
            llds16(gb + 768, Bsw1 + (size_t)c * 8);
        }
        __syncthreads();
#pragma unroll
        for (int ks = 0; ks < 2; ks++) {
            f16x8 a[4], bh[4], bl[4];
#pragma unroll
            for (int i = 0; i < 4; i++) {
                int row = wm * 64 + i * 16 + l15;
                a[i] = *(const f16x8*)&Asw[row * 64 + (((ks * 4 + q) ^ (row & 7)) << 3)];
            }
#pragma unroll
            for (int jj = 0; jj < 4; jj++) {
                int row = wn * 64 + jj * 16 + l15;
                int off = row * 64 + (((ks * 4 + q) ^ (row & 7)) << 3);
                bh[jj] = *(const f16x8*)&Bsw0[off];
                bl[jj] = *(const f16x8*)&Bsw1[off];
            }
#pragma unroll
            for (int i = 0; i < 4; i++)
#pragma unroll
                for (int jj = 0; jj < 4; jj++) {
                    acc[i][jj] = __builtin_amdgcn_mfma_f32_16x16x32_f16(a[i], bh[jj], acc[i][jj], 0, 0, 0);
                    acc[i][jj] = __builtin_amdgcn_mfma_f32_16x16x32_f16(a[i], bl[jj], acc[i][jj], 0, 0, 0);
                }
        }
        __syncthreads();
    }

    // epilogue: stats + LDS repack (two 64-row halves) + coalesced float4 stores
#pragma unroll
    for (int half = 0; half < 2; half++) {
        if (wm == half) {
#pragma unroll
            for (int i = 0; i < 4; i++) {
#pragma unroll
                for (int ii = 0; ii < 4; ii++) {
                    const int rl = i * 16 + q * 4 + ii;            // 0..63
                    const int rg = m0 + bm + half * 64 + rl;
                    float s = 0.f, s2 = 0.f;
#pragma unroll
                    for (int jj = 0; jj < 4; jj++) {
                        const int cl = wn * 64 + jj * 16 + l15;
                        const int cg = bn + cl;
                        float v = acc[i][jj][ii] * INV_WSCALE;
                        v = (cg < 3600) ? v + bias[cg / 15] : 0.f;
                        Cf[rl][cl] = v;
                        s += v; s2 += v * v;
                    }
#pragma unroll
                    for (int off = 1; off < 16; off <<= 1) {
                        s += __shfl_xor(s, off);
                        s2 += __shfl_xor(s2, off);
                    }
                    if (l15 == 0) {
                        atomicAdd(&ssum[rg], s);
                        atomicAdd(&ssq[rg], s2);
                    }
                }
            }
        }
        __syncthreads();
        const int rbase = m0 + bm + half * 64;
#pragma unroll
        for (int it = 0; it < 8; it++) {
            int c = it * 256 + tid;            // 2048 chunks of 4 floats
            int r = c >> 5, s = (c & 31) * 4;
            int gc = bn + s;
            if (gc < 3600)
                *(float4*)(H1 + (size_t)(rbase + r) * 3600 + gc) = *(const float4*)&Cf[r][s];
        }
        __syncthreads();
    }
}

// ---------------- conv2: split-K GEMM, 3-term, LN+ELU fused on A --------------
// grid (128 Mblk, 4 Kchunk). Accumulates scaled partials into h2 [16384][96] f32.
__global__ __launch_bounds__(256) void conv2_pk(
    const float* __restrict__ H1, const f16* __restrict__ Bh, const f16* __restrict__ Bl,
    const float* __restrict__ ssum, const float* __restrict__ ssq,
    const float* __restrict__ lnw, const float* __restrict__ lnb,
    float* __restrict__ h2)
{
    const int tid = threadIdx.x;
    const int wave = tid >> 6, lane = tid & 63;
    const int l15 = lane & 15, q = lane >> 4;
    const int wm = wave >> 1, wn = wave & 1;
    const int bm = blockIdx.x * 128;
    const int chunk = blockIdx.y;
    const int t0 = (chunk == 0) ? 0 : 15 + 14 * (chunk - 1);   // 0,15,29,43
    const int nt = (chunk == 0) ? 15 : 14;

    __shared__ __align__(16) f16 Ah[128][88];      // 176B stride: 2-way = free
    __shared__ __align__(16) f16 Al[128][88];
    __shared__ __align__(16) f16 Bsw[2][96 * 64];  // swizzled
    __shared__ float mur[128], rsr[128];

    if (tid < 128) {
        float mu = ssum[bm + tid] * (1.f / 3600.f);
        float var = ssq[bm + tid] * (1.f / 3600.f) - mu * mu;
        mur[tid] = mu;
        rsr[tid] = rsqrtf(fmaxf(var, 0.f) + 1e-5f);
    }
    __syncthreads();

    floatx4 acc[4][3];
#pragma unroll
    for (int i = 0; i < 4; i++)
#pragma unroll
        for (int j = 0; j < 3; j++) acc[i][j] = (floatx4){0.f, 0.f, 0.f, 0.f};

    for (int t = 0; t < nt; t++) {
        const int k0 = (t0 + t) * 64;
#pragma unroll
        for (int it = 0; it < 3; it++) {
            int c = it * 256 + tid;                // 768 chunks/plane
            int row = c >> 3;
            int seg = (c & 7) ^ (row & 7);
            llds16(Bh + (size_t)row * 3648 + k0 + seg * 8, &Bsw[0][0] + (size_t)c * 8);
            llds16(Bl + (size_t)row * 3648 + k0 + seg * 8, &Bsw[1][0] + (size_t)c * 8);
        }
#pragma unroll
        for (int it = 0; it < 8; it++) {
            int idx = it * 256 + tid;              // 2048 float4
            int r = idx >> 4, c4 = (idx & 15) * 4;
            int gc = k0 + c4;
            f16x4 hv = {(f16)0.f, (f16)0.f, (f16)0.f, (f16)0.f};
            f16x4 lv = hv;
            if (gc < 3600) {
                float4 v  = *(const float4*)(H1 + (size_t)(bm + r) * 3600 + gc);
                float4 w4 = *(const float4*)(lnw + gc);
                float4 b4 = *(const float4*)(lnb + gc);
                float mu = mur[r], rs = rsr[r];
                float z0 = (v.x - mu) * rs * w4.x + b4.x; z0 = z0 > 0.f ? z0 : (__expf(z0) - 1.f);
                float z1 = (v.y - mu) * rs * w4.y + b4.y; z1 = z1 > 0.f ? z1 : (__expf(z1) - 1.f);
                float z2 = (v.z - mu) * rs * w4.z + b4.z; z2 = z2 > 0.f ? z2 : (__expf(z2) - 1.f);
                float z3 = (v.w - mu) * rs * w4.w + b4.w; z3 = z3 > 0.f ? z3 : (__expf(z3) - 1.f);
                f16 h0 = (f16)z0, h1 = (f16)z1, h2v = (f16)z2, h3v = (f16)z3;
                hv = (f16x4){h0, h1, h2v, h3v};
                lv = (f16x4){(f16)(z0 - (float)h0), (f16)(z1 - (float)h1),
                             (f16)(z2 - (float)h2v), (f16)(z3 - (float)h3v)};
            }
            *(f16x4*)&Ah[r][c4] = hv;
            *(f16x4*)&Al[r][c4] = lv;
        }
        __syncthreads();
#pragma unroll
        for (int ks = 0; ks < 2; ks++) {
            f16x8 ah[4], al[4], bh[3], bl[3];
#pragma unroll
            for (int i = 0; i < 4; i++) {
                ah[i] = *(const f16x8*)&Ah[wm * 64 + i * 16 + l15][ks * 32 + q * 8];
                al[i] = *(const f16x8*)&Al[wm * 64 + i * 16 + l15][ks * 32 + q * 8];
            }
#pragma unroll
            for (int j = 0; j < 3; j++) {
                int row = wn * 48 + j * 16 + l15;
                int off = row * 64 + (((ks * 4 + q) ^ (row & 7)) << 3);
                bh[j] = *(const f16x8*)&Bsw[0][off];
                bl[j] = *(const f16x8*)&Bsw[1][off];
            }
#pragma unroll
            for (int i = 0; i < 4; i++)
#pragma unroll
                for (int j = 0; j < 3; j++) {
                    acc[i][j] = __builtin_amdgcn_mfma_f32_16x16x32_f16(ah[i], bh[j], acc[i][j], 0, 0, 0);
                    acc[i][j] = __builtin_amdgcn_mfma_f32_16x16x32_f16(al[i], bh[j], acc[i][j], 0, 0, 0);
                    acc[i][j] = __builtin_amdgcn_mfma_f32_16x16x32_f16(ah[i], bl[j], acc[i][j], 0, 0, 0);
                }
        }
        __syncthreads();
    }

#pragma unroll
    for (int i = 0; i < 4; i++)
#pragma unroll
        for (int ii = 0; ii < 4; ii++) {
            const int rg = bm + wm * 64 + i * 16 + q * 4 + ii;
#pragma unroll
            for (int j = 0; j < 3; j++) {
                const int cg = wn * 48 + j * 16 + l15;
                atomicAdd(&h2[(size_t)rg * 96 + cg], acc[i][j][ii]);
            }
        }
}

// ---------------- extraction: DFT -> f,a,off; fc -> phase; sinusoid -> sig ----
__global__ void extract(const float* __restrict__ h2, const float* __restrict__ c2b,
                        const float* __restrict__ fcw, const float* __restrict__ fcb,
                        f16* __restrict__ sig)
{
    __shared__ float ct[7][15], st[7][15], fw[180], fb[12];
    const int tid = threadIdx.x;
    if (tid < 105) {
        int kk = tid / 15, t = tid - kk * 15;
        double ang = (2.0 * 3.141592653589793 / 15.0) * (double)((kk + 1) * t);
        ct[kk][t] = (float)cos(ang);
        st[kk][t] = (float)sin(ang);
    }
    if (tid < 180) fw[tid] = fcw[tid];
    if (tid < 12) fb[tid] = fcb[tid];
    __syncthreads();

    const int task = blockIdx.x * 256 + tid;       // 98304 = 16384*6 exactly
    const int r = task / 6, e = task - (task / 6) * 6;
    float h[15];
    float mean = 0.f;
#pragma unroll
    for (int t = 0; t < 15; t++) {
        h[t] = h2[(size_t)r * 96 + e * 15 + t] * INV_WSCALE + c2b[e];
        mean += h[t];
    }
    mean *= (1.f / 15.f);
    float psum = 0.f, fsum = 0.f;
#pragma unroll
    for (int kk = 0; kk < 7; kk++) {
        float re = 0.f, im = 0.f;
#pragma unroll
        for (int t = 0; t < 15; t++) { re += h[t] * ct[kk][t]; im -= h[t] * st[kk][t]; }
        float p = re * re + im * im;
        psum += p;
        fsum += p * ((float)(kk + 1) * (10.f / 3.f));
    }
    float f = fsum / psum;
    float a = 2.f * sqrtf(psum) * (1.f / 15.f);
    float v0 = fb[e * 2 + 0], v1 = fb[e * 2 + 1];
#pragma unroll
    for (int t = 0; t < 15; t++) {
        v0 += h[t] * fw[(e * 2 + 0) * 15 + t];
        v1 += h[t] * fw[(e * 2 + 1) * 15 + t];
    }
    float ph = atan2f(v1, v0) * (1.f / TPI);
    f16* outp = sig + (size_t)r * 96 + e * 15;
#pragma unroll
    for (int t = 0; t < 15; t++) {
        float arg = f * (-0.15f + (float)t * (0.3f / 14.f)) + ph;
        outp[t] = (f16)(a * sinpif(2.f * arg) + mean);
    }
    if (e == 0) {
#pragma unroll
        for (int p2 = 0; p2 < 6; p2++) sig[(size_t)r * 96 + 90 + p2] = (f16)0.f;
    }
}

// ---------------- deconv1: single-K GEMM + stats + LDS-repacked f16 store -----
// A = sigb [16384][96], B = D1 [3712][96]. C = h3 [16384] stride 3648 (cols<3600).
__global__ __launch_bounds__(256) void deconv1_k(
    const f16* __restrict__ A, const f16* __restrict__ B,
    f16* __restrict__ C, const float* __restrict__ bias,
    float* __restrict__ ssum, float* __restrict__ ssq)
{
    const int tid = threadIdx.x;
    const int wave = tid >> 6, lane = tid & 63;
    const int l15 = lane & 15, q = lane >> 4;
    const int wm = wave >> 1, wn = wave & 1;
    const int bm = blockIdx.x * 128, bn = blockIdx.y * 128;

    __shared__ __align__(16) char smem[53248];
    f16 (*As)[104] = (f16(*)[104])smem;            // 128 x (96+8)
    f16 (*Bs)[104] = (f16(*)[104])(smem + 26624);
    f16 (*Ct)[136] = (f16(*)[136])smem;            // repack, aliases As/Bs

    // stage A and B: 1536 16B-chunks each (128 rows x 12)
#pragma unroll
    for (int it = 0; it < 6; it++) {
        int c = it * 256 + tid;
        int r = c / 12, s = c - r * 12;
        *(uint4*)&As[r][s * 8] = *(const uint4*)(A + (size_t)(bm + r) * 96 + s * 8);
        *(uint4*)&Bs[r][s * 8] = *(const uint4*)(B + (size_t)(bn + r) * 96 + s * 8);
    }
    __syncthreads();

    floatx4 acc[4][4];
#pragma unroll
    for (int i = 0; i < 4; i++)
#pragma unroll
        for (int j = 0; j < 4; j++) acc[i][j] = (floatx4){0.f, 0.f, 0.f, 0.f};

#pragma unroll
    for (int ks = 0; ks < 3; ks++) {
        f16x8 af[4], bf[4];
#pragma unroll
        for (int i = 0; i < 4; i++)
            af[i] = *(const f16x8*)&As[wm * 64 + i * 16 + l15][ks * 32 + q * 8];
#pragma unroll
        for (int j = 0; j < 4; j++)
            bf[j] = *(const f16x8*)&Bs[wn * 64 + j * 16 + l15][ks * 32 + q * 8];
#pragma unroll
        for (int i = 0; i < 4; i++)
#pragma unroll
            for (int j = 0; j < 4; j++)
                acc[i][j] = __builtin_amdgcn_mfma_f32_16x16x32_f16(af[i], bf[j], acc[i][j], 0, 0, 0);
    }
    __syncthreads();

    // stats + repack to LDS (f16)
#pragma unroll
    for (int i = 0; i < 4; i++) {
#pragma unroll
        for (int ii = 0; ii < 4; ii++) {
            const int rl = wm * 64 + i * 16 + q * 4 + ii;
            const int rg = bm + rl;
            float s = 0.f, s2 = 0.f;
#pragma unroll
            for (int jj = 0; jj < 4; jj++) {
                const int cl = wn * 64 + jj * 16 + l15;
                const int cg = bn + cl;
                float v = acc[i][jj][ii];
                v = (cg < 3600) ? v + bias[cg / 15] : 0.f;
                Ct[rl][cl] = (f16)v;
                s += v; s2 += v * v;
            }
#pragma unroll
            for (int off = 1; off < 16; off <<= 1) {
                s += __shfl_xor(s, off);
                s2 += __shfl_xor(s2, off);
            }
            if (l15 == 0) {
                atomicAdd(&ssum[rg], s);
                atomicAdd(&ssq[rg], s2);
            }
        }
    }
    __syncthreads();

    // coalesced 16B stores (skip cols >= 3600; never read downstream)
#pragma unroll
    for (int it = 0; it < 8; it++) {
        int c = it * 256 + tid;                    // 2048 chunks of 8 f16
        int r = c >> 4, s = (c & 15) * 8;
        int gc = bn + s;
        if (gc < 3600)
            *(uint4*)(C + (size_t)(bm + r) * 3648 + gc) = *(const uint4*)&Ct[r][s];
    }
}

// ---------------- deconv2: LN+ELU fused on A, split-K, atomic out -------------
__global__ __launch_bounds__(256) void deconv2_ln(
    const f16* __restrict__ h3, const f16* __restrict__ D2,
    const float* __restrict__ ssum, const float* __restrict__ ssq,
    const float* __restrict__ lnw, const float* __restrict__ lnb,
    const float* __restrict__ bias, float* __restrict__ out)
{
    const int tid = threadIdx.x;
    const int wave = tid >> 6, lane = tid & 63;
    const int l15 = lane & 15, q = lane >> 4;
    const int bm = blockIdx.x * 64;
    const int chunk = blockIdx.y;
    const int t0 = (chunk == 0) ? 0 : 15 + 14 * (chunk - 1);
    const int nt = (chunk == 0) ? 15 : 14;

    __shared__ __align__(16) f16 As[64][88];
    __shared__ __align__(16) f16 Bs[48][88];
    __shared__ float mur[64], rsr[64];

    if (tid < 64) {
        float mu = ssum[bm + tid] * (1.f / 3600.f);
        float var = ssq[bm + tid] * (1.f / 3600.f) - mu * mu;
        mur[tid] = mu;
        rsr[tid] = rsqrtf(fmaxf(var, 0.f) + 1e-5f);
    }
    __syncthreads();

    floatx4 acc[3];
#pragma unroll
    for (int j = 0; j < 3; j++) acc[j] = (floatx4){0.f, 0.f, 0.f, 0.f};

    for (int t = 0; t < nt; t++) {
        const int k0 = (t0 + t) * 64;
#pragma unroll
        for (int it = 0; it < 2; it++) {
            int idx = it * 256 + tid;              // 512 f16x8 chunks
            int r = idx >> 3, s = idx & 7;
            int gc = k0 + s * 8;
            f16x8 o = {};
            if (gc < 3600) {
                f16x8 v = *(const f16x8*)(h3 + (size_t)(bm + r) * 3648 + gc);
                float mu = mur[r], rs = rsr[r];
#pragma unroll
                for (int e = 0; e < 8; e++) {
                    float y = ((float)v[e] - mu) * rs * lnw[gc + e] + lnb[gc + e];
                    o[e] = (f16)(y > 0.f ? y : (__expf(y) - 1.f));
                }
            }
            *(f16x8*)&As[r][s * 8] = o;
        }
        for (int idx = tid; idx < 384; idx += 256) {
            int r = idx >> 3, s = idx & 7;
            *(uint4*)&Bs[r][s * 8] = *(const uint4*)(D2 + (size_t)r * 3648 + k0 + s * 8);
        }
        __syncthreads();
#pragma unroll
        for (int ks = 0; ks < 2; ks++) {
            f16x8 a = *(const f16x8*)&As[wave * 16 + l15][ks * 32 + q * 8];
#pragma unroll
            for (int j = 0; j < 3; j++) {
                f16x8 b = *(const f16x8*)&Bs[j * 16 + l15][ks * 32 + q * 8];
                acc[j] = __builtin_amdgcn_mfma_f32_16x16x32_f16(a, b, acc[j], 0, 0, 0);
            }
        }
        __syncthreads();
    }

#pragma unroll
    for (int j = 0; j < 3; j++)
#pragma unroll
        for (int ii = 0; ii < 4; ii++) {
            int rg = bm + wave * 16 + q * 4 + ii;
            int cg = j * 16 + l15;
            float v = acc[j][ii];
            if (chunk == 0) v += bias[cg];
            atomicAdd(&out[(size_t)rg * 48 + cg], v);
        }
}

// ---------------- launch ----------------
extern "C" void kernel_launch(void* const* d_in, const int* in_sizes, int n_in,
                              void* d_out, int out_size, void* d_ws, size_t ws_size,
                              hipStream_t stream)
{
    const float* x   = (const float*)d_in[0];
    const float* w1  = (const float*)d_in[1];
    const float* b1  = (const float*)d_in[2];
    const float* nw1 = (const float*)d_in[3];
    const float* nb1 = (const float*)d_in[4];
    const float* w2  = (const float*)d_in[5];
    const float* b2  = (const float*)d_in[6];
    const float* fcw = (const float*)d_in[7];
    const float* fcb = (const float*)d_in[8];
    const float* dw1 = (const float*)d_in[9];
    const float* db1 = (const float*)d_in[10];
    const float* nw2 = (const float*)d_in[11];
    const float* nb2 = (const float*)d_in[12];
    const float* dw2 = (const float*)d_in[13];
    const float* db2 = (const float*)d_in[14];
    float* out = (float*)d_out;

    // workspace layout — total 262,641,664 B (proven footprint)
    f16* B2  = (f16*)d_ws;                     // 3712*1536
    f16* W2h = B2  + (size_t)3712 * 1536;      // 96*3648 x2
    f16* W2l = W2h + (size_t)96 * 3648;
    f16* D1  = W2l + (size_t)96 * 3648;        // 3712*96
    f16* D2  = D1  + (size_t)3712 * 96;        // 48*3648
    float* stats = (float*)(D2 + (size_t)48 * 3648);   // 4*16384
    float* s1 = stats;
    float* q1 = stats + 16384;
    float* s3 = stats + 32768;
    float* q3 = stats + 49152;
    float* h2 = stats + 4 * 16384;             // 16384*96 f32
    f16* sigb = (f16*)(h2 + (size_t)16384 * 96);   // 16384*96
    f16* Xh   = (f16*)h2;                      // 8192*768 f16 (aliases h2+sigb+pad)
    float* H1 = (float*)((char*)h2 + 12582912);    // 16384*3600 f32
    f16* h3   = (f16*)H1;                      // reused after conv2 consumed H1

    hipMemsetAsync(stats, 0, (size_t)4 * 16384 * 4, stream);
    hipMemsetAsync(out, 0, (size_t)16384 * 48 * 4, stream);

    prep_w<<<2048, 256, 0, stream>>>(w1, w2, dw1, dw2, B2, W2h, W2l, D1, D2);

    // conv1 in two M-halves (Xh aliases h2/sigb, dead until conv2)
    prep_xh<<<1536, 256, 0, stream>>>(x, Xh);
    gemm1_async<<<dim3(64, 29), 256, 0, stream>>>(Xh, B2, H1, b1, s1, q1, 0);
    prep_xh<<<1536, 256, 0, stream>>>(x + (size_t)8192 * 720, Xh);
    gemm1_async<<<dim3(64, 29), 256, 0, stream>>>(Xh, B2, H1, b1, s1, q1, 8192);

    // h2 zero AFTER Xh is dead (aliased)
    hipMemsetAsync(h2, 0, (size_t)16384 * 96 * 4, stream);

    // conv2 (3-term split, LN+ELU fused, split-K x4) -> h2 partials (scaled)
    conv2_pk<<<dim3(128, 4), 256, 0, stream>>>(H1, W2h, W2l, s1, q1, nw1, nb1, h2);

    // extraction -> sig
    extract<<<384, 256, 0, stream>>>(h2, b2, fcw, fcb, sigb);

    // deconv1: [16384,96] x [3712,96]^T -> h3 f16 + stats (coalesced store)
    deconv1_k<<<dim3(128, 29), 256, 0, stream>>>(sigb, D1, h3, db1, s3, q3);

    // deconv2 (LN+ELU fused, split-K x4, last timestep) -> out
    deconv2_ln<<<dim3(256, 4), 256, 0, stream>>>(h3, D2, s3, q3, nw2, nb2, db2, out);
}

// Round 9
// 701.299 us; speedup vs baseline: 1.0182x; 1.0182x over previous
//
#include <hip/hip_runtime.h>

typedef _Float16 f16;
typedef _Float16 f16x8 __attribute__((ext_vector_type(8)));
typedef _Float16 f16x4 __attribute__((ext_vector_type(4)));
typedef float floatx4 __attribute__((ext_vector_type(4)));

#define TPI 6.283185307179586f
#define WSCALE 256.0f
#define INV_WSCALE (1.0f / 256.0f)

// async global->LDS, 16B per lane; LDS dest = wave-uniform base + lane*16
__device__ __forceinline__ void llds16(const f16* g, f16* l)
{
    __builtin_amdgcn_global_load_lds(
        (const __attribute__((address_space(1))) unsigned int*)g,
        (__attribute__((address_space(3))) unsigned int*)l, 16, 0, 0);
}

// ---------------- prep: Xh half (8192 rows) fp32 -> f16, K-pad 720->768 -------
__global__ void prep_xh(const float* __restrict__ x, f16* __restrict__ Xh)
{
    const int TT = 8192 * 96;          // f16x8 groups
    for (int i = blockIdx.x * 256 + threadIdx.x; i < TT; i += gridDim.x * 256) {
        int r = i / 96, g = (i - r * 96) * 8;
        f16x8 o = {};
        if (g < 720) {
            const float* xp = x + (size_t)r * 720 + g;
            float4 v0 = *(const float4*)xp;
            float4 v1 = *(const float4*)(xp + 4);
            o = (f16x8){(f16)v0.x, (f16)v0.y, (f16)v0.z, (f16)v0.w,
                        (f16)v1.x, (f16)v1.y, (f16)v1.z, (f16)v1.w};
        }
        *(f16x8*)(Xh + (size_t)r * 768 + g) = o;
    }
}

// ---------------- prep: weights (B2 packed split planes x256) + small mats ----
__global__ void prep_w(const float* __restrict__ w1, const float* __restrict__ w2,
                       const float* __restrict__ dw1, const float* __restrict__ dw2,
                       f16* __restrict__ B2,
                       f16* __restrict__ W2h, f16* __restrict__ W2l,
                       f16* __restrict__ D1, f16* __restrict__ D2)
{
    const int T1 = 3712 * 768;   // W1 im2col [n=o*15+t][k=c*15+s] -> B2 [n][bh|bl]
    const int T2 = 96 * 3648;    // W2 [n=e*15+t][k=m*15+s] -> planes
    const int T3 = 3712 * 96;    // D1 [n=m*15+t][k=e*15+s]
    const int T4 = 48 * 3648;    // D2 [o][k=m*15+s], s>=7 (last output position)
    const int TT = T1 + T2 + T3 + T4;
    for (int i = blockIdx.x * 256 + threadIdx.x; i < TT; i += gridDim.x * 256) {
        if (i < T1) {
            int n = i / 768, k = i - n * 768;
            float v = 0.f;
            if (n < 3600 && k < 720) {
                int o = n / 15, t = n - o * 15, c = k / 15, s = k - c * 15, d = s - t + 7;
                if (d >= 0 && d < 15) v = w1[(o * 48 + c) * 15 + d];
            }
            v *= WSCALE;
            f16 hi = (f16)v;
            f16* row = B2 + (size_t)n * 1536 + k;
            row[0] = hi;
            row[768] = (f16)(v - (float)hi);
        } else if (i < T1 + T2) {
            int j = i - T1;
            int n = j / 3648, k = j - n * 3648;
            float v = 0.f;
            if (n < 90 && k < 3600) {
                int e = n / 15, t = n - e * 15, m = k / 15, s = k - m * 15, d = s - t + 7;
                if (d >= 0 && d < 15) v = w2[(e * 240 + m) * 15 + d];
            }
            v *= WSCALE;
            f16 hi = (f16)v;
            W2h[j] = hi; W2l[j] = (f16)(v - (float)hi);
        } else if (i < T1 + T2 + T3) {
            int j = i - T1 - T2;
            int n = j / 96, k = j - n * 96;
            float v = 0.f;
            if (n < 3600 && k < 90) {
                int m = n / 15, t = n - m * 15, e = k / 15, s = k - e * 15, d = s - t + 7;
                if (d >= 0 && d < 15) v = dw1[(m * 6 + e) * 15 + d];
            }
            D1[j] = (f16)v;
        } else {
            int j = i - T1 - T2 - T3;
            int o = j / 3648, k = j - o * 3648;
            float v = 0.f;
            if (k < 3600) {
                int m = k / 15, s = k - m * 15;
                if (s >= 7) v = dw2[(o * 240 + m) * 15 + (s - 7)];
            }
            D2[j] = (f16)v;
        }
    }
}

// ---------------- conv1: 2-term split GEMM, fully-async staging ---------------
__global__ __launch_bounds__(256, 3) void gemm1_async(
    const f16* __restrict__ Xh, const f16* __restrict__ B2,
    float* __restrict__ H1, const float* __restrict__ bias,
    float* __restrict__ ssum, float* __restrict__ ssq, int m0)
{
    const int tid = threadIdx.x;
    const int wave = tid >> 6, lane = tid & 63;
    const int l15 = lane & 15, q = lane >> 4;
    const int wm = wave >> 1, wn = wave & 1;
    const int bm = blockIdx.x * 128, bn = blockIdx.y * 128;

    __shared__ __align__(16) f16 Asw[128 * 64];        // swizzled 16B chunks
    __shared__ __align__(16) f16 Bsw[2][128 * 64];     // [0]=bh, [1]=bl, swizzled

    floatx4 acc[4][4];
#pragma unroll
    for (int i = 0; i < 4; i++)
#pragma unroll
        for (int j = 0; j < 4; j++) acc[i][j] = (floatx4){0.f, 0.f, 0.f, 0.f};

    for (int kt = 0; kt < 12; kt++) {
        const int k0 = kt * 64;
#pragma unroll
        for (int it = 0; it < 4; it++) {
            int c = it * 256 + tid;                    // 1024 chunks/plane
            int row = c >> 3;
            int seg = (c & 7) ^ (row & 7);
            llds16(Xh + (size_t)(bm + row) * 768 + k0 + seg * 8, Asw + (size_t)c * 8);
            const f16* gb = B2 + (size_t)(bn + row) * 1536 + k0 + seg * 8;
            llds16(gb,       &Bsw[0][0] + (size_t)c * 8);
            llds16(gb + 768, &Bsw[1][0] + (size_t)c * 8);
        }
        __syncthreads();
#pragma unroll
        for (int ks = 0; ks < 2; ks++) {
            f16x8 a[4], bh[4], bl[4];
#pragma unroll
            for (int i = 0; i < 4; i++) {
                int row = wm * 64 + i * 16 + l15;
                a[i] = *(const f16x8*)&Asw[row * 64 + (((ks * 4 + q) ^ (row & 7)) << 3)];
            }
#pragma unroll
            for (int jj = 0; jj < 4; jj++) {
                int row = wn * 64 + jj * 16 + l15;
                int off = row * 64 + (((ks * 4 + q) ^ (row & 7)) << 3);
                bh[jj] = *(const f16x8*)&Bsw[0][off];
                bl[jj] = *(const f16x8*)&Bsw[1][off];
            }
#pragma unroll
            for (int i = 0; i < 4; i++)
#pragma unroll
                for (int jj = 0; jj < 4; jj++) {
                    acc[i][jj] = __builtin_amdgcn_mfma_f32_16x16x32_f16(a[i], bh[jj], acc[i][jj], 0, 0, 0);
                    acc[i][jj] = __builtin_amdgcn_mfma_f32_16x16x32_f16(a[i], bl[jj], acc[i][jj], 0, 0, 0);
                }
        }
        __syncthreads();
    }

#pragma unroll
    for (int i = 0; i < 4; i++) {
#pragma unroll
        for (int ii = 0; ii < 4; ii++) {
            const int rg = m0 + bm + wm * 64 + i * 16 + q * 4 + ii;
            float s = 0.f, s2 = 0.f;
#pragma unroll
            for (int jj = 0; jj < 4; jj++) {
                const int cg = bn + wn * 64 + jj * 16 + l15;
                float v = acc[i][jj][ii] * INV_WSCALE;
                if (cg < 3600) {
                    v += bias[cg / 15];
                    H1[(size_t)rg * 3600 + cg] = v;
                } else v = 0.f;
                s += v; s2 += v * v;
            }
#pragma unroll
            for (int off = 1; off < 16; off <<= 1) {
                s += __shfl_xor(s, off);
                s2 += __shfl_xor(s2, off);
            }
            if (l15 == 0) {
                atomicAdd(&ssum[rg], s);
                atomicAdd(&ssq[rg], s2);
            }
        }
    }
}

// ---------------- conv2: split-K GEMM, 3-term, LN+ELU fused on A --------------
__global__ __launch_bounds__(256) void conv2_pk(
    const float* __restrict__ H1, const f16* __restrict__ Bh, const f16* __restrict__ Bl,
    const float* __restrict__ ssum, const float* __restrict__ ssq,
    const float* __restrict__ lnw, const float* __restrict__ lnb,
    float* __restrict__ h2)
{
    const int tid = threadIdx.x;
    const int wave = tid >> 6, lane = tid & 63;
    const int l15 = lane & 15, q = lane >> 4;
    const int wm = wave >> 1, wn = wave & 1;
    const int bm = blockIdx.x * 128;
    const int chunk = blockIdx.y;
    const int t0 = (chunk == 0) ? 0 : 15 + 14 * (chunk - 1);   // 0,15,29,43
    const int nt = (chunk == 0) ? 15 : 14;

    __shared__ __align__(16) f16 Ah[128][88];
    __shared__ __align__(16) f16 Al[128][88];
    __shared__ __align__(16) f16 Bsw[2][96 * 64];
    __shared__ float mur[128], rsr[128];

    if (tid < 128) {
        float mu = ssum[bm + tid] * (1.f / 3600.f);
        float var = ssq[bm + tid] * (1.f / 3600.f) - mu * mu;
        mur[tid] = mu;
        rsr[tid] = rsqrtf(fmaxf(var, 0.f) + 1e-5f);
    }
    __syncthreads();

    floatx4 acc[4][3];
#pragma unroll
    for (int i = 0; i < 4; i++)
#pragma unroll
        for (int j = 0; j < 3; j++) acc[i][j] = (floatx4){0.f, 0.f, 0.f, 0.f};

    for (int t = 0; t < nt; t++) {
        const int k0 = (t0 + t) * 64;
#pragma unroll
        for (int it = 0; it < 3; it++) {
            int c = it * 256 + tid;                // 768 chunks/plane
            int row = c >> 3;
            int seg = (c & 7) ^ (row & 7);
            llds16(Bh + (size_t)row * 3648 + k0 + seg * 8, &Bsw[0][0] + (size_t)c * 8);
            llds16(Bl + (size_t)row * 3648 + k0 + seg * 8, &Bsw[1][0] + (size_t)c * 8);
        }
#pragma unroll
        for (int it = 0; it < 8; it++) {
            int idx = it * 256 + tid;              // 2048 float4
            int r = idx >> 4, c4 = (idx & 15) * 4;
            int gc = k0 + c4;
            f16x4 hv = {(f16)0.f, (f16)0.f, (f16)0.f, (f16)0.f};
            f16x4 lv = hv;
            if (gc < 3600) {
                float4 v  = *(const float4*)(H1 + (size_t)(bm + r) * 3600 + gc);
                float4 w4 = *(const float4*)(lnw + gc);
                float4 b4 = *(const float4*)(lnb + gc);
                float mu = mur[r], rs = rsr[r];
                float z0 = (v.x - mu) * rs * w4.x + b4.x; z0 = z0 > 0.f ? z0 : (__expf(z0) - 1.f);
                float z1 = (v.y - mu) * rs * w4.y + b4.y; z1 = z1 > 0.f ? z1 : (__expf(z1) - 1.f);
                float z2 = (v.z - mu) * rs * w4.z + b4.z; z2 = z2 > 0.f ? z2 : (__expf(z2) - 1.f);
                float z3 = (v.w - mu) * rs * w4.w + b4.w; z3 = z3 > 0.f ? z3 : (__expf(z3) - 1.f);
                f16 h0 = (f16)z0, h1 = (f16)z1, h2v = (f16)z2, h3v = (f16)z3;
                hv = (f16x4){h0, h1, h2v, h3v};
                lv = (f16x4){(f16)(z0 - (float)h0), (f16)(z1 - (float)h1),
                             (f16)(z2 - (float)h2v), (f16)(z3 - (float)h3v)};
            }
            *(f16x4*)&Ah[r][c4] = hv;
            *(f16x4*)&Al[r][c4] = lv;
        }
        __syncthreads();
#pragma unroll
        for (int ks = 0; ks < 2; ks++) {
            f16x8 ah[4], al[4], bh[3], bl[3];
#pragma unroll
            for (int i = 0; i < 4; i++) {
                ah[i] = *(const f16x8*)&Ah[wm * 64 + i * 16 + l15][ks * 32 + q * 8];
                al[i] = *(const f16x8*)&Al[wm * 64 + i * 16 + l15][ks * 32 + q * 8];
            }
#pragma unroll
            for (int j = 0; j < 3; j++) {
                int row = wn * 48 + j * 16 + l15;
                int off = row * 64 + (((ks * 4 + q) ^ (row & 7)) << 3);
                bh[j] = *(const f16x8*)&Bsw[0][off];
                bl[j] = *(const f16x8*)&Bsw[1][off];
            }
#pragma unroll
            for (int i = 0; i < 4; i++)
#pragma unroll
                for (int j = 0; j < 3; j++) {
                    acc[i][j] = __builtin_amdgcn_mfma_f32_16x16x32_f16(ah[i], bh[j], acc[i][j], 0, 0, 0);
                    acc[i][j] = __builtin_amdgcn_mfma_f32_16x16x32_f16(al[i], bh[j], acc[i][j], 0, 0, 0);
                    acc[i][j] = __builtin_amdgcn_mfma_f32_16x16x32_f16(ah[i], bl[j], acc[i][j], 0, 0, 0);
                }
        }
        __syncthreads();
    }

#pragma unroll
    for (int i = 0; i < 4; i++)
#pragma unroll
        for (int ii = 0; ii < 4; ii++) {
            const int rg = bm + wm * 64 + i * 16 + q * 4 + ii;
#pragma unroll
            for (int j = 0; j < 3; j++) {
                const int cg = wn * 48 + j * 16 + l15;
                atomicAdd(&h2[(size_t)rg * 96 + cg], acc[i][j][ii]);
            }
        }
}

// ---------------- extraction: DFT -> f,a,off; fc -> phase; sinusoid -> sig ----
__global__ void extract(const float* __restrict__ h2, const float* __restrict__ c2b,
                        const float* __restrict__ fcw, const float* __restrict__ fcb,
                        f16* __restrict__ sig)
{
    __shared__ float ct[7][15], st[7][15], fw[180], fb[12];
    const int tid = threadIdx.x;
    if (tid < 105) {
        int kk = tid / 15, t = tid - kk * 15;
        double ang = (2.0 * 3.141592653589793 / 15.0) * (double)((kk + 1) * t);
        ct[kk][t] = (float)cos(ang);
        st[kk][t] = (float)sin(ang);
    }
    if (tid < 180) fw[tid] = fcw[tid];
    if (tid < 12) fb[tid] = fcb[tid];
    __syncthreads();

    const int task = blockIdx.x * 256 + tid;       // 98304 = 16384*6 exactly
    const int r = task / 6, e = task - (task / 6) * 6;
    float h[15];
    float mean = 0.f;
#pragma unroll
    for (int t = 0; t < 15; t++) {
        h[t] = h2[(size_t)r * 96 + e * 15 + t] * INV_WSCALE + c2b[e];
        mean += h[t];
    }
    mean *= (1.f / 15.f);
    float psum = 0.f, fsum = 0.f;
#pragma unroll
    for (int kk = 0; kk < 7; kk++) {
        float re = 0.f, im = 0.f;
#pragma unroll
        for (int t = 0; t < 15; t++) { re += h[t] * ct[kk][t]; im -= h[t] * st[kk][t]; }
        float p = re * re + im * im;
        psum += p;
        fsum += p * ((float)(kk + 1) * (10.f / 3.f));
    }
    float f = fsum / psum;
    float a = 2.f * sqrtf(psum) * (1.f / 15.f);
    float v0 = fb[e * 2 + 0], v1 = fb[e * 2 + 1];
#pragma unroll
    for (int t = 0; t < 15; t++) {
        v0 += h[t] * fw[(e * 2 + 0) * 15 + t];
        v1 += h[t] * fw[(e * 2 + 1) * 15 + t];
    }
    float ph = atan2f(v1, v0) * (1.f / TPI);
    f16* outp = sig + (size_t)r * 96 + e * 15;
#pragma unroll
    for (int t = 0; t < 15; t++) {
        float arg = f * (-0.15f + (float)t * (0.3f / 14.f)) + ph;
        outp[t] = (f16)(a * sinpif(2.f * arg) + mean);
    }
    if (e == 0) {
#pragma unroll
        for (int p2 = 0; p2 < 6; p2++) sig[(size_t)r * 96 + 90 + p2] = (f16)0.f;
    }
}

// ---------------- pass 1: deconv1 LN-stats only (no h3 store) -----------------
__global__ __launch_bounds__(256) void deconv1_stats(
    const f16* __restrict__ sigb, const f16* __restrict__ D1,
    const float* __restrict__ bias, float* __restrict__ ssum, float* __restrict__ ssq)
{
    const int tid = threadIdx.x;
    const int w = tid >> 6, lane = tid & 63;
    const int l15 = lane & 15, q = lane >> 4;
    const int bm = blockIdx.x * 64;

    __shared__ __align__(16) f16 As[64][104];
    __shared__ __align__(16) f16 Bs[128][104];

#pragma unroll
    for (int it = 0; it < 3; it++) {               // 768 chunks: 64 rows x 12
        int c = it * 256 + tid;
        int r = c / 12, s = c - r * 12;
        *(uint4*)&As[r][s * 8] = *(const uint4*)(sigb + (size_t)(bm + r) * 96 + s * 8);
    }

    float sa[4] = {0.f, 0.f, 0.f, 0.f}, qa[4] = {0.f, 0.f, 0.f, 0.f};

    for (int bn = 0; bn < 3712; bn += 128) {
        __syncthreads();                           // protect prior Bs readers (+As ready, it 0)
#pragma unroll
        for (int it = 0; it < 6; it++) {           // 1536 chunks: 128 rows x 12
            int c = it * 256 + tid;
            int r = c / 12, s = c - r * 12;
            *(uint4*)&Bs[r][s * 8] = *(const uint4*)(D1 + (size_t)(bn + r) * 96 + s * 8);
        }
        __syncthreads();

        floatx4 acc[8];
#pragma unroll
        for (int j = 0; j < 8; j++) acc[j] = (floatx4){0.f, 0.f, 0.f, 0.f};
#pragma unroll
        for (int ks = 0; ks < 3; ks++) {
            f16x8 a = *(const f16x8*)&As[w * 16 + l15][ks * 32 + q * 8];
#pragma unroll
            for (int j = 0; j < 8; j++) {
                f16x8 b = *(const f16x8*)&Bs[j * 16 + l15][ks * 32 + q * 8];
                acc[j] = __builtin_amdgcn_mfma_f32_16x16x32_f16(a, b, acc[j], 0, 0, 0);
            }
        }
#pragma unroll
        for (int j = 0; j < 8; j++) {
            const int cg = bn + j * 16 + l15;
            if (cg < 3600) {
                float bv = bias[cg / 15];
#pragma unroll
                for (int ii = 0; ii < 4; ii++) {
                    float v = acc[j][ii] + bv;
                    sa[ii] += v; qa[ii] += v * v;
                }
            }
        }
    }

#pragma unroll
    for (int ii = 0; ii < 4; ii++) {
#pragma unroll
        for (int off = 1; off < 16; off <<= 1) {
            sa[ii] += __shfl_xor(sa[ii], off);
            qa[ii] += __shfl_xor(qa[ii], off);
        }
        if (l15 == 0) {
            const int rg = bm + w * 16 + q * 4 + ii;
            ssum[rg] = sa[ii];                     // unique writer: plain store
            ssq[rg]  = qa[ii];
        }
    }
}

// ---------------- pass 2: fused deconv1-recompute + LN + ELU + deconv2 --------
// grid 256 x BM=64. h3 never touches HBM. Wave w owns output rows w*16..w*16+15
// in the second GEMM (fix for the all-waves-duplicate bug of round 8).
__global__ __launch_bounds__(256) void fused_deconv(
    const f16* __restrict__ sigb, const f16* __restrict__ D1, const f16* __restrict__ D2,
    const float* __restrict__ ssum, const float* __restrict__ ssq,
    const float* __restrict__ lnw, const float* __restrict__ lnb,
    const float* __restrict__ b1, const float* __restrict__ b2,
    float* __restrict__ out)
{
    const int tid = threadIdx.x;
    const int w = tid >> 6, lane = tid & 63;
    const int l15 = lane & 15, q = lane >> 4;
    const int bm = blockIdx.x * 64;

    __shared__ __align__(16) f16 As[64][104];
    __shared__ __align__(16) f16 D1s[64][104];
    __shared__ __align__(16) f16 hs[64][72];
    __shared__ __align__(16) f16 D2s[48][72];
    __shared__ float mur[64], rsr[64];

    if (tid < 64) {
        float mu = ssum[bm + tid] * (1.f / 3600.f);
        float var = ssq[bm + tid] * (1.f / 3600.f) - mu * mu;
        mur[tid] = mu;
        rsr[tid] = rsqrtf(fmaxf(var, 0.f) + 1e-5f);
    }
#pragma unroll
    for (int it = 0; it < 3; it++) {                   // sigb rows: 768 chunks
        int c = it * 256 + tid;
        int r = c / 12, s = c - r * 12;
        *(uint4*)&As[r][s * 8] = *(const uint4*)(sigb + (size_t)(bm + r) * 96 + s * 8);
    }

    floatx4 acc_out[3];
#pragma unroll
    for (int j = 0; j < 3; j++) acc_out[j] = (floatx4){0.f, 0.f, 0.f, 0.f};

    for (int kt = 0; kt < 57; kt++) {
        const int k0 = kt * 64;
        __syncthreads();                               // protect prior D1s/D2s/hs readers
#pragma unroll
        for (int it = 0; it < 3; it++) {               // D1 rows k0..k0+63: 768 chunks
            int c = it * 256 + tid;
            int r = c / 12, s = c - r * 12;
            *(uint4*)&D1s[r][s * 8] = *(const uint4*)(D1 + (size_t)(k0 + r) * 96 + s * 8);
        }
        for (int c = tid; c < 384; c += 256) {         // D2 48 rows x 8 chunks
            int r = c >> 3, s = c & 7;
            *(uint4*)&D2s[r][s * 8] = *(const uint4*)(D2 + (size_t)r * 3648 + k0 + s * 8);
        }
        __syncthreads();

        // T-GEMM: h3 tile [64 rows][64 cols], wave w owns cols w*16..w*16+15
        floatx4 acc4[4];
#pragma unroll
        for (int i = 0; i < 4; i++) acc4[i] = (floatx4){0.f, 0.f, 0.f, 0.f};
#pragma unroll
        for (int ks = 0; ks < 3; ks++) {
            f16x8 bt = *(const f16x8*)&D1s[w * 16 + l15][ks * 32 + q * 8];
#pragma unroll
            for (int i = 0; i < 4; i++) {
                f16x8 at = *(const f16x8*)&As[i * 16 + l15][ks * 32 + q * 8];
                acc4[i] = __builtin_amdgcn_mfma_f32_16x16x32_f16(at, bt, acc4[i], 0, 0, 0);
            }
        }
        // bias + LN + ELU, C-layout -> A-layout via LDS
        const int cg = k0 + w * 16 + l15;
        float bv = (cg < 3600) ? b1[cg / 15] : 0.f;
        float lw = (cg < 3600) ? lnw[cg] : 0.f;
        float lb = (cg < 3600) ? lnb[cg] : 0.f;
#pragma unroll
        for (int i = 0; i < 4; i++)
#pragma unroll
            for (int ii = 0; ii < 4; ii++) {
                const int m = i * 16 + q * 4 + ii;
                f16 hv = (f16)0.f;
                if (cg < 3600) {
                    float y = (acc4[i][ii] + bv - mur[m]) * rsr[m] * lw + lb;
                    hv = (f16)(y > 0.f ? y : (__expf(y) - 1.f));
                }
                hs[m][w * 16 + l15] = hv;
            }
        __syncthreads();
        // out accumulation: wave w computes rows w*16..w*16+15 only
#pragma unroll
        for (int ks = 0; ks < 2; ks++) {
            f16x8 a = *(const f16x8*)&hs[w * 16 + l15][ks * 32 + q * 8];
#pragma unroll
            for (int j = 0; j < 3; j++) {
                f16x8 b = *(const f16x8*)&D2s[j * 16 + l15][ks * 32 + q * 8];
                acc_out[j] = __builtin_amdgcn_mfma_f32_16x16x32_f16(a, b, acc_out[j], 0, 0, 0);
            }
        }
    }

    // direct store: wave w owns rows bm + w*16 .. +15 (unique writer)
#pragma unroll
    for (int j = 0; j < 3; j++)
#pragma unroll
        for (int ii = 0; ii < 4; ii++) {
            const int rg = bm + w * 16 + q * 4 + ii;
            const int c = j * 16 + l15;
            out[(size_t)rg * 48 + c] = acc_out[j][ii] + b2[c];
        }
}

// ---------------- launch ----------------
extern "C" void kernel_launch(void* const* d_in, const int* in_sizes, int n_in,
                              void* d_out, int out_size, void* d_ws, size_t ws_size,
                              hipStream_t stream)
{
    const float* x   = (const float*)d_in[0];
    const float* w1  = (const float*)d_in[1];
    const float* b1  = (const float*)d_in[2];
    const float* nw1 = (const float*)d_in[3];
    const float* nb1 = (const float*)d_in[4];
    const float* w2  = (const float*)d_in[5];
    const float* b2  = (const float*)d_in[6];
    const float* fcw = (const float*)d_in[7];
    const float* fcb = (const float*)d_in[8];
    const float* dw1 = (const float*)d_in[9];
    const float* db1 = (const float*)d_in[10];
    const float* nw2 = (const float*)d_in[11];
    const float* nb2 = (const float*)d_in[12];
    const float* dw2 = (const float*)d_in[13];
    const float* db2 = (const float*)d_in[14];
    float* out = (float*)d_out;

    // workspace layout — total 262,641,664 B (proven footprint)
    f16* B2  = (f16*)d_ws;                     // 3712*1536
    f16* W2h = B2  + (size_t)3712 * 1536;      // 96*3648 x2
    f16* W2l = W2h + (size_t)96 * 3648;
    f16* D1  = W2l + (size_t)96 * 3648;        // 3712*96
    f16* D2  = D1  + (size_t)3712 * 96;        // 48*3648
    float* stats = (float*)(D2 + (size_t)48 * 3648);   // 4*16384
    float* s1 = stats;
    float* q1 = stats + 16384;
    float* s3 = stats + 32768;
    float* q3 = stats + 49152;
    float* h2 = stats + 4 * 16384;             // 16384*96 f32
    f16* sigb = (f16*)(h2 + (size_t)16384 * 96);   // 16384*96
    f16* Xh   = (f16*)h2;                      // 8192*768 f16 (aliases h2+sigb+pad)
    float* H1 = (float*)((char*)h2 + 12582912);    // 16384*3600 f32

    hipMemsetAsync(stats, 0, (size_t)4 * 16384 * 4, stream);

    prep_w<<<2048, 256, 0, stream>>>(w1, w2, dw1, dw2, B2, W2h, W2l, D1, D2);

    // conv1 in two M-halves (Xh aliases h2/sigb, dead until conv2)
    prep_xh<<<1536, 256, 0, stream>>>(x, Xh);
    gemm1_async<<<dim3(64, 29), 256, 0, stream>>>(Xh, B2, H1, b1, s1, q1, 0);
    prep_xh<<<1536, 256, 0, stream>>>(x + (size_t)8192 * 720, Xh);
    gemm1_async<<<dim3(64, 29), 256, 0, stream>>>(Xh, B2, H1, b1, s1, q1, 8192);

    // h2 zero AFTER Xh is dead (aliased)
    hipMemsetAsync(h2, 0, (size_t)16384 * 96 * 4, stream);

    // conv2 (3-term split, LN+ELU fused, split-K x4) -> h2 partials (scaled)
    conv2_pk<<<dim3(128, 4), 256, 0, stream>>>(H1, W2h, W2l, s1, q1, nw1, nb1, h2);

    // extraction -> sig
    extract<<<384, 256, 0, stream>>>(h2, b2, fcw, fcb, sigb);

    // deconv path: stats pass (no h3 store), then fused recompute+LN+ELU+deconv2
    deconv1_stats<<<256, 256, 0, stream>>>(sigb, D1, db1, s3, q3);
    fused_deconv<<<256, 256, 0, stream>>>(sigb, D1, D2, s3, q3, nw2, nb2, db1, db2, out);
}

// Round 10
// 591.504 us; speedup vs baseline: 1.2071x; 1.1856x over previous
//
#include <hip/hip_runtime.h>

typedef _Float16 f16;
typedef _Float16 f16x8 __attribute__((ext_vector_type(8)));
typedef _Float16 f16x4 __attribute__((ext_vector_type(4)));
typedef float floatx4 __attribute__((ext_vector_type(4)));

#define TPI 6.283185307179586f
#define WSCALE 256.0f
#define INV_WSCALE (1.0f / 256.0f)

// async global->LDS, 16B per lane; LDS dest = wave-uniform base + lane*16
__device__ __forceinline__ void llds16(const f16* g, f16* l)
{
    __builtin_amdgcn_global_load_lds(
        (const __attribute__((address_space(1))) unsigned int*)g,
        (__attribute__((address_space(3))) unsigned int*)l, 16, 0, 0);
}

// ---------------- prep: Xh half (8192 rows) fp32 -> f16, K-pad 720->768 -------
__global__ void prep_xh(const float* __restrict__ x, f16* __restrict__ Xh)
{
    const int TT = 8192 * 96;          // f16x8 groups
    for (int i = blockIdx.x * 256 + threadIdx.x; i < TT; i += gridDim.x * 256) {
        int r = i / 96, g = (i - r * 96) * 8;
        f16x8 o = {};
        if (g < 720) {
            const float* xp = x + (size_t)r * 720 + g;
            float4 v0 = *(const float4*)xp;
            float4 v1 = *(const float4*)(xp + 4);
            o = (f16x8){(f16)v0.x, (f16)v0.y, (f16)v0.z, (f16)v0.w,
                        (f16)v1.x, (f16)v1.y, (f16)v1.z, (f16)v1.w};
        }
        *(f16x8*)(Xh + (size_t)r * 768 + g) = o;
    }
}

// ---------------- prep: weights (B2 packed split planes x256) + small mats ----
__global__ void prep_w(const float* __restrict__ w1, const float* __restrict__ w2,
                       const float* __restrict__ dw1, const float* __restrict__ dw2,
                       f16* __restrict__ B2,
                       f16* __restrict__ W2h, f16* __restrict__ W2l,
                       f16* __restrict__ D1, f16* __restrict__ D2)
{
    const int T1 = 3712 * 768;   // W1 im2col [n=o*15+t][k=c*15+s] -> B2 [n][bh|bl]
    const int T2 = 96 * 3648;    // W2 [n=e*15+t][k=m*15+s] -> planes
    const int T3 = 3712 * 96;    // D1 [n=m*15+t][k=e*15+s]
    const int T4 = 48 * 3648;    // D2 [o][k=m*15+s], s>=7 (last output position)
    const int TT = T1 + T2 + T3 + T4;
    for (int i = blockIdx.x * 256 + threadIdx.x; i < TT; i += gridDim.x * 256) {
        if (i < T1) {
            int n = i / 768, k = i - n * 768;
            float v = 0.f;
            if (n < 3600 && k < 720) {
                int o = n / 15, t = n - o * 15, c = k / 15, s = k - c * 15, d = s - t + 7;
                if (d >= 0 && d < 15) v = w1[(o * 48 + c) * 15 + d];
            }
            v *= WSCALE;
            f16 hi = (f16)v;
            f16* row = B2 + (size_t)n * 1536 + k;
            row[0] = hi;
            row[768] = (f16)(v - (float)hi);
        } else if (i < T1 + T2) {
            int j = i - T1;
            int n = j / 3648, k = j - n * 3648;
            float v = 0.f;
            if (n < 90 && k < 3600) {
                int e = n / 15, t = n - e * 15, m = k / 15, s = k - m * 15, d = s - t + 7;
                if (d >= 0 && d < 15) v = w2[(e * 240 + m) * 15 + d];
            }
            v *= WSCALE;
            f16 hi = (f16)v;
            W2h[j] = hi; W2l[j] = (f16)(v - (float)hi);
        } else if (i < T1 + T2 + T3) {
            int j = i - T1 - T2;
            int n = j / 96, k = j - n * 96;
            float v = 0.f;
            if (n < 3600 && k < 90) {
                int m = n / 15, t = n - m * 15, e = k / 15, s = k - e * 15, d = s - t + 7;
                if (d >= 0 && d < 15) v = dw1[(m * 6 + e) * 15 + d];
            }
            D1[j] = (f16)v;
        } else {
            int j = i - T1 - T2 - T3;
            int o = j / 3648, k = j - o * 3648;
            float v = 0.f;
            if (k < 3600) {
                int m = k / 15, s = k - m * 15;
                if (s >= 7) v = dw2[(o * 240 + m) * 15 + (s - 7)];
            }
            D2[j] = (f16)v;
        }
    }
}

// ---------------- conv1: 2-term split GEMM, fully-async staging ---------------
__global__ __launch_bounds__(256, 3) void gemm1_async(
    const f16* __restrict__ Xh, const f16* __restrict__ B2,
    float* __restrict__ H1, const float* __restrict__ bias,
    float* __restrict__ ssum, float* __restrict__ ssq, int m0)
{
    const int tid = threadIdx.x;
    const int wave = tid >> 6, lane = tid & 63;
    const int l15 = lane & 15, q = lane >> 4;
    const int wm = wave >> 1, wn = wave & 1;
    const int bm = blockIdx.x * 128, bn = blockIdx.y * 128;

    __shared__ __align__(16) f16 Asw[128 * 64];        // swizzled 16B chunks
    __shared__ __align__(16) f16 Bsw[2][128 * 64];     // [0]=bh, [1]=bl, swizzled

    floatx4 acc[4][4];
#pragma unroll
    for (int i = 0; i < 4; i++)
#pragma unroll
        for (int j = 0; j < 4; j++) acc[i][j] = (floatx4){0.f, 0.f, 0.f, 0.f};

    for (int kt = 0; kt < 12; kt++) {
        const int k0 = kt * 64;
#pragma unroll
        for (int it = 0; it < 4; it++) {
            int c = it * 256 + tid;                    // 1024 chunks/plane
            int row = c >> 3;
            int seg = (c & 7) ^ (row & 7);
            llds16(Xh + (size_t)(bm + row) * 768 + k0 + seg * 8, Asw + (size_t)c * 8);
            const f16* gb = B2 + (size_t)(bn + row) * 1536 + k0 + seg * 8;
            llds16(gb,       &Bsw[0][0] + (size_t)c * 8);
            llds16(gb + 768, &Bsw[1][0] + (size_t)c * 8);
        }
        __syncthreads();
#pragma unroll
        for (int ks = 0; ks < 2; ks++) {
            f16x8 a[4], bh[4], bl[4];
#pragma unroll
            for (int i = 0; i < 4; i++) {
                int row = wm * 64 + i * 16 + l15;
                a[i] = *(const f16x8*)&Asw[row * 64 + (((ks * 4 + q) ^ (row & 7)) << 3)];
            }
#pragma unroll
            for (int jj = 0; jj < 4; jj++) {
                int row = wn * 64 + jj * 16 + l15;
                int off = row * 64 + (((ks * 4 + q) ^ (row & 7)) << 3);
                bh[jj] = *(const f16x8*)&Bsw[0][off];
                bl[jj] = *(const f16x8*)&Bsw[1][off];
            }
#pragma unroll
            for (int i = 0; i < 4; i++)
#pragma unroll
                for (int jj = 0; jj < 4; jj++) {
                    acc[i][jj] = __builtin_amdgcn_mfma_f32_16x16x32_f16(a[i], bh[jj], acc[i][jj], 0, 0, 0);
                    acc[i][jj] = __builtin_amdgcn_mfma_f32_16x16x32_f16(a[i], bl[jj], acc[i][jj], 0, 0, 0);
                }
        }
        __syncthreads();
    }

#pragma unroll
    for (int i = 0; i < 4; i++) {
#pragma unroll
        for (int ii = 0; ii < 4; ii++) {
            const int rg = m0 + bm + wm * 64 + i * 16 + q * 4 + ii;
            float s = 0.f, s2 = 0.f;
#pragma unroll
            for (int jj = 0; jj < 4; jj++) {
                const int cg = bn + wn * 64 + jj * 16 + l15;
                float v = acc[i][jj][ii] * INV_WSCALE;
                if (cg < 3600) {
                    v += bias[cg / 15];
                    H1[(size_t)rg * 3600 + cg] = v;
                } else v = 0.f;
                s += v; s2 += v * v;
            }
#pragma unroll
            for (int off = 1; off < 16; off <<= 1) {
                s += __shfl_xor(s, off);
                s2 += __shfl_xor(s2, off);
            }
            if (l15 == 0) {
                atomicAdd(&ssum[rg], s);
                atomicAdd(&ssq[rg], s2);
            }
        }
    }
}

// ---------------- conv2: split-K GEMM, 3-term, LN+ELU fused on A --------------
__global__ __launch_bounds__(256) void conv2_pk(
    const float* __restrict__ H1, const f16* __restrict__ Bh, const f16* __restrict__ Bl,
    const float* __restrict__ ssum, const float* __restrict__ ssq,
    const float* __restrict__ lnw, const float* __restrict__ lnb,
    float* __restrict__ h2)
{
    const int tid = threadIdx.x;
    const int wave = tid >> 6, lane = tid & 63;
    const int l15 = lane & 15, q = lane >> 4;
    const int wm = wave >> 1, wn = wave & 1;
    const int bm = blockIdx.x * 128;
    const int chunk = blockIdx.y;
    const int t0 = (chunk == 0) ? 0 : 15 + 14 * (chunk - 1);   // 0,15,29,43
    const int nt = (chunk == 0) ? 15 : 14;

    __shared__ __align__(16) f16 Ah[128][88];
    __shared__ __align__(16) f16 Al[128][88];
    __shared__ __align__(16) f16 Bsw[2][96 * 64];
    __shared__ float mur[128], rsr[128];

    if (tid < 128) {
        float mu = ssum[bm + tid] * (1.f / 3600.f);
        float var = ssq[bm + tid] * (1.f / 3600.f) - mu * mu;
        mur[tid] = mu;
        rsr[tid] = rsqrtf(fmaxf(var, 0.f) + 1e-5f);
    }
    __syncthreads();

    floatx4 acc[4][3];
#pragma unroll
    for (int i = 0; i < 4; i++)
#pragma unroll
        for (int j = 0; j < 3; j++) acc[i][j] = (floatx4){0.f, 0.f, 0.f, 0.f};

    for (int t = 0; t < nt; t++) {
        const int k0 = (t0 + t) * 64;
#pragma unroll
        for (int it = 0; it < 3; it++) {
            int c = it * 256 + tid;                // 768 chunks/plane
            int row = c >> 3;
            int seg = (c & 7) ^ (row & 7);
            llds16(Bh + (size_t)row * 3648 + k0 + seg * 8, &Bsw[0][0] + (size_t)c * 8);
            llds16(Bl + (size_t)row * 3648 + k0 + seg * 8, &Bsw[1][0] + (size_t)c * 8);
        }
#pragma unroll
        for (int it = 0; it < 8; it++) {
            int idx = it * 256 + tid;              // 2048 float4
            int r = idx >> 4, c4 = (idx & 15) * 4;
            int gc = k0 + c4;
            f16x4 hv = {(f16)0.f, (f16)0.f, (f16)0.f, (f16)0.f};
            f16x4 lv = hv;
            if (gc < 3600) {
                float4 v  = *(const float4*)(H1 + (size_t)(bm + r) * 3600 + gc);
                float4 w4 = *(const float4*)(lnw + gc);
                float4 b4 = *(const float4*)(lnb + gc);
                float mu = mur[r], rs = rsr[r];
                float z0 = (v.x - mu) * rs * w4.x + b4.x; z0 = z0 > 0.f ? z0 : (__expf(z0) - 1.f);
                float z1 = (v.y - mu) * rs * w4.y + b4.y; z1 = z1 > 0.f ? z1 : (__expf(z1) - 1.f);
                float z2 = (v.z - mu) * rs * w4.z + b4.z; z2 = z2 > 0.f ? z2 : (__expf(z2) - 1.f);
                float z3 = (v.w - mu) * rs * w4.w + b4.w; z3 = z3 > 0.f ? z3 : (__expf(z3) - 1.f);
                f16 h0 = (f16)z0, h1 = (f16)z1, h2v = (f16)z2, h3v = (f16)z3;
                hv = (f16x4){h0, h1, h2v, h3v};
                lv = (f16x4){(f16)(z0 - (float)h0), (f16)(z1 - (float)h1),
                             (f16)(z2 - (float)h2v), (f16)(z3 - (float)h3v)};
            }
            *(f16x4*)&Ah[r][c4] = hv;
            *(f16x4*)&Al[r][c4] = lv;
        }
        __syncthreads();
#pragma unroll
        for (int ks = 0; ks < 2; ks++) {
            f16x8 ah[4], al[4], bh[3], bl[3];
#pragma unroll
            for (int i = 0; i < 4; i++) {
                ah[i] = *(const f16x8*)&Ah[wm * 64 + i * 16 + l15][ks * 32 + q * 8];
                al[i] = *(const f16x8*)&Al[wm * 64 + i * 16 + l15][ks * 32 + q * 8];
            }
#pragma unroll
            for (int j = 0; j < 3; j++) {
                int row = wn * 48 + j * 16 + l15;
                int off = row * 64 + (((ks * 4 + q) ^ (row & 7)) << 3);
                bh[j] = *(const f16x8*)&Bsw[0][off];
                bl[j] = *(const f16x8*)&Bsw[1][off];
            }
#pragma unroll
            for (int i = 0; i < 4; i++)
#pragma unroll
                for (int j = 0; j < 3; j++) {
                    acc[i][j] = __builtin_amdgcn_mfma_f32_16x16x32_f16(ah[i], bh[j], acc[i][j], 0, 0, 0);
                    acc[i][j] = __builtin_amdgcn_mfma_f32_16x16x32_f16(al[i], bh[j], acc[i][j], 0, 0, 0);
                    acc[i][j] = __builtin_amdgcn_mfma_f32_16x16x32_f16(ah[i], bl[j], acc[i][j], 0, 0, 0);
                }
        }
        __syncthreads();
    }

#pragma unroll
    for (int i = 0; i < 4; i++)
#pragma unroll
        for (int ii = 0; ii < 4; ii++) {
            const int rg = bm + wm * 64 + i * 16 + q * 4 + ii;
#pragma unroll
            for (int j = 0; j < 3; j++) {
                const int cg = wn * 48 + j * 16 + l15;
                atomicAdd(&h2[(size_t)rg * 96 + cg], acc[i][j][ii]);
            }
        }
}

// ---------------- extraction: DFT -> f,a,off; fc -> phase; sinusoid -> sig ----
__global__ void extract(const float* __restrict__ h2, const float* __restrict__ c2b,
                        const float* __restrict__ fcw, const float* __restrict__ fcb,
                        f16* __restrict__ sig)
{
    __shared__ float ct[7][15], st[7][15], fw[180], fb[12];
    const int tid = threadIdx.x;
    if (tid < 105) {
        int kk = tid / 15, t = tid - kk * 15;
        double ang = (2.0 * 3.141592653589793 / 15.0) * (double)((kk + 1) * t);
        ct[kk][t] = (float)cos(ang);
        st[kk][t] = (float)sin(ang);
    }
    if (tid < 180) fw[tid] = fcw[tid];
    if (tid < 12) fb[tid] = fcb[tid];
    __syncthreads();

    const int task = blockIdx.x * 256 + tid;       // 98304 = 16384*6 exactly
    const int r = task / 6, e = task - (task / 6) * 6;
    float h[15];
    float mean = 0.f;
#pragma unroll
    for (int t = 0; t < 15; t++) {
        h[t] = h2[(size_t)r * 96 + e * 15 + t] * INV_WSCALE + c2b[e];
        mean += h[t];
    }
    mean *= (1.f / 15.f);
    float psum = 0.f, fsum = 0.f;
#pragma unroll
    for (int kk = 0; kk < 7; kk++) {
        float re = 0.f, im = 0.f;
#pragma unroll
        for (int t = 0; t < 15; t++) { re += h[t] * ct[kk][t]; im -= h[t] * st[kk][t]; }
        float p = re * re + im * im;
        psum += p;
        fsum += p * ((float)(kk + 1) * (10.f / 3.f));
    }
    float f = fsum / psum;
    float a = 2.f * sqrtf(psum) * (1.f / 15.f);
    float v0 = fb[e * 2 + 0], v1 = fb[e * 2 + 1];
#pragma unroll
    for (int t = 0; t < 15; t++) {
        v0 += h[t] * fw[(e * 2 + 0) * 15 + t];
        v1 += h[t] * fw[(e * 2 + 1) * 15 + t];
    }
    float ph = atan2f(v1, v0) * (1.f / TPI);
    f16* outp = sig + (size_t)r * 96 + e * 15;
#pragma unroll
    for (int t = 0; t < 15; t++) {
        float arg = f * (-0.15f + (float)t * (0.3f / 14.f)) + ph;
        outp[t] = (f16)(a * sinpif(2.f * arg) + mean);
    }
    if (e == 0) {
#pragma unroll
        for (int p2 = 0; p2 < 6; p2++) sig[(size_t)r * 96 + 90 + p2] = (f16)0.f;
    }
}

// ---------------- pass 1: deconv1 LN-stats only, split-N x2 -------------------
__global__ __launch_bounds__(256) void deconv1_stats(
    const f16* __restrict__ sigb, const f16* __restrict__ D1,
    const float* __restrict__ bias, float* __restrict__ ssum, float* __restrict__ ssq)
{
    const int tid = threadIdx.x;
    const int w = tid >> 6, lane = tid & 63;
    const int l15 = lane & 15, q = lane >> 4;
    const int bm = blockIdx.x * 64;
    const int tn0 = (blockIdx.y == 0) ? 0 : 15;      // N-tile range
    const int tn1 = (blockIdx.y == 0) ? 15 : 29;

    __shared__ __align__(16) f16 As[64][104];
    __shared__ __align__(16) f16 Bs[128][104];

#pragma unroll
    for (int it = 0; it < 3; it++) {               // 768 chunks: 64 rows x 12
        int c = it * 256 + tid;
        int r = c / 12, s = c - r * 12;
        *(uint4*)&As[r][s * 8] = *(const uint4*)(sigb + (size_t)(bm + r) * 96 + s * 8);
    }

    float sa[4] = {0.f, 0.f, 0.f, 0.f}, qa[4] = {0.f, 0.f, 0.f, 0.f};

    for (int tn = tn0; tn < tn1; tn++) {
        const int bn = tn * 128;
        __syncthreads();                           // protect prior Bs readers (+As ready)
#pragma unroll
        for (int it = 0; it < 6; it++) {           // 1536 chunks: 128 rows x 12
            int c = it * 256 + tid;
            int r = c / 12, s = c - r * 12;
            *(uint4*)&Bs[r][s * 8] = *(const uint4*)(D1 + (size_t)(bn + r) * 96 + s * 8);
        }
        __syncthreads();

        floatx4 acc[8];
#pragma unroll
        for (int j = 0; j < 8; j++) acc[j] = (floatx4){0.f, 0.f, 0.f, 0.f};
#pragma unroll
        for (int ks = 0; ks < 3; ks++) {
            f16x8 a = *(const f16x8*)&As[w * 16 + l15][ks * 32 + q * 8];
#pragma unroll
            for (int j = 0; j < 8; j++) {
                f16x8 b = *(const f16x8*)&Bs[j * 16 + l15][ks * 32 + q * 8];
                acc[j] = __builtin_amdgcn_mfma_f32_16x16x32_f16(a, b, acc[j], 0, 0, 0);
            }
        }
#pragma unroll
        for (int j = 0; j < 8; j++) {
            const int cg = bn + j * 16 + l15;
            if (cg < 3600) {
                float bv = bias[cg / 15];
#pragma unroll
                for (int ii = 0; ii < 4; ii++) {
                    float v = acc[j][ii] + bv;
                    sa[ii] += v; qa[ii] += v * v;
                }
            }
        }
    }

#pragma unroll
    for (int ii = 0; ii < 4; ii++) {
#pragma unroll
        for (int off = 1; off < 16; off <<= 1) {
            sa[ii] += __shfl_xor(sa[ii], off);
            qa[ii] += __shfl_xor(qa[ii], off);
        }
        if (l15 == 0) {
            const int rg = bm + w * 16 + q * 4 + ii;
            atomicAdd(&ssum[rg], sa[ii]);
            atomicAdd(&ssq[rg], qa[ii]);
        }
    }
}

// ---------------- pass 2: fused deconv1-recompute + LN + ELU + deconv2 --------
// grid (256, 4): M-block x K-chunk. h3 never touches HBM; partials atomicAdd'd.
__global__ __launch_bounds__(256) void fused_deconv(
    const f16* __restrict__ sigb, const f16* __restrict__ D1, const f16* __restrict__ D2,
    const float* __restrict__ ssum, const float* __restrict__ ssq,
    const float* __restrict__ lnw, const float* __restrict__ lnb,
    const float* __restrict__ b1, const float* __restrict__ b2,
    float* __restrict__ out)
{
    const int tid = threadIdx.x;
    const int w = tid >> 6, lane = tid & 63;
    const int l15 = lane & 15, q = lane >> 4;
    const int bm = blockIdx.x * 64;
    const int chunk = blockIdx.y;
    const int kt0 = (chunk == 0) ? 0 : 15 + 14 * (chunk - 1);  // 0,15,29,43
    const int nkt = (chunk == 0) ? 15 : 14;

    __shared__ __align__(16) f16 As[64][104];
    __shared__ __align__(16) f16 D1s[64][104];
    __shared__ __align__(16) f16 hs[64][72];
    __shared__ __align__(16) f16 D2s[48][72];
    __shared__ float mur[64], rsr[64];

    if (tid < 64) {
        float mu = ssum[bm + tid] * (1.f / 3600.f);
        float var = ssq[bm + tid] * (1.f / 3600.f) - mu * mu;
        mur[tid] = mu;
        rsr[tid] = rsqrtf(fmaxf(var, 0.f) + 1e-5f);
    }
#pragma unroll
    for (int it = 0; it < 3; it++) {                   // sigb rows: 768 chunks
        int c = it * 256 + tid;
        int r = c / 12, s = c - r * 12;
        *(uint4*)&As[r][s * 8] = *(const uint4*)(sigb + (size_t)(bm + r) * 96 + s * 8);
    }

    floatx4 acc_out[3];
#pragma unroll
    for (int j = 0; j < 3; j++) acc_out[j] = (floatx4){0.f, 0.f, 0.f, 0.f};

    for (int t = 0; t < nkt; t++) {
        const int k0 = (kt0 + t) * 64;
        __syncthreads();                               // protect prior D1s/D2s/hs readers
#pragma unroll
        for (int it = 0; it < 3; it++) {               // D1 rows k0..k0+63: 768 chunks
            int c = it * 256 + tid;
            int r = c / 12, s = c - r * 12;
            *(uint4*)&D1s[r][s * 8] = *(const uint4*)(D1 + (size_t)(k0 + r) * 96 + s * 8);
        }
        for (int c = tid; c < 384; c += 256) {         // D2 48 rows x 8 chunks
            int r = c >> 3, s = c & 7;
            *(uint4*)&D2s[r][s * 8] = *(const uint4*)(D2 + (size_t)r * 3648 + k0 + s * 8);
        }
        __syncthreads();

        // T-GEMM: h3 tile [64 rows][64 cols], wave w owns cols w*16..w*16+15
        floatx4 acc4[4];
#pragma unroll
        for (int i = 0; i < 4; i++) acc4[i] = (floatx4){0.f, 0.f, 0.f, 0.f};
#pragma unroll
        for (int ks = 0; ks < 3; ks++) {
            f16x8 bt = *(const f16x8*)&D1s[w * 16 + l15][ks * 32 + q * 8];
#pragma unroll
            for (int i = 0; i < 4; i++) {
                f16x8 at = *(const f16x8*)&As[i * 16 + l15][ks * 32 + q * 8];
                acc4[i] = __builtin_amdgcn_mfma_f32_16x16x32_f16(at, bt, acc4[i], 0, 0, 0);
            }
        }
        // bias + LN + ELU, C-layout -> A-layout via LDS
        const int cg = k0 + w * 16 + l15;
        float bv = (cg < 3600) ? b1[cg / 15] : 0.f;
        float lw = (cg < 3600) ? lnw[cg] : 0.f;
        float lb = (cg < 3600) ? lnb[cg] : 0.f;
#pragma unroll
        for (int i = 0; i < 4; i++)
#pragma unroll
            for (int ii = 0; ii < 4; ii++) {
                const int m = i * 16 + q * 4 + ii;
                f16 hv = (f16)0.f;
                if (cg < 3600) {
                    float y = (acc4[i][ii] + bv - mur[m]) * rsr[m] * lw + lb;
                    hv = (f16)(y > 0.f ? y : (__expf(y) - 1.f));
                }
                hs[m][w * 16 + l15] = hv;
            }
        __syncthreads();
        // out accumulation: wave w computes rows w*16..w*16+15 only
#pragma unroll
        for (int ks = 0; ks < 2; ks++) {
            f16x8 a = *(const f16x8*)&hs[w * 16 + l15][ks * 32 + q * 8];
#pragma unroll
            for (int j = 0; j < 3; j++) {
                f16x8 b = *(const f16x8*)&D2s[j * 16 + l15][ks * 32 + q * 8];
                acc_out[j] = __builtin_amdgcn_mfma_f32_16x16x32_f16(a, b, acc_out[j], 0, 0, 0);
            }
        }
    }

    // partial store: wave w owns rows bm + w*16 .. +15; chunks sum via atomics
#pragma unroll
    for (int j = 0; j < 3; j++)
#pragma unroll
        for (int ii = 0; ii < 4; ii++) {
            const int rg = bm + w * 16 + q * 4 + ii;
            const int c = j * 16 + l15;
            float v = acc_out[j][ii];
            if (chunk == 0) v += b2[c];
            atomicAdd(&out[(size_t)rg * 48 + c], v);
        }
}

// ---------------- launch ----------------
extern "C" void kernel_launch(void* const* d_in, const int* in_sizes, int n_in,
                              void* d_out, int out_size, void* d_ws, size_t ws_size,
                              hipStream_t stream)
{
    const float* x   = (const float*)d_in[0];
    const float* w1  = (const float*)d_in[1];
    const float* b1  = (const float*)d_in[2];
    const float* nw1 = (const float*)d_in[3];
    const float* nb1 = (const float*)d_in[4];
    const float* w2  = (const float*)d_in[5];
    const float* b2  = (const float*)d_in[6];
    const float* fcw = (const float*)d_in[7];
    const float* fcb = (const float*)d_in[8];
    const float* dw1 = (const float*)d_in[9];
    const float* db1 = (const float*)d_in[10];
    const float* nw2 = (const float*)d_in[11];
    const float* nb2 = (const float*)d_in[12];
    const float* dw2 = (const float*)d_in[13];
    const float* db2 = (const float*)d_in[14];
    float* out = (float*)d_out;

    // workspace layout — total 262,641,664 B (proven footprint)
    f16* B2  = (f16*)d_ws;                     // 3712*1536
    f16* W2h = B2  + (size_t)3712 * 1536;      // 96*3648 x2
    f16* W2l = W2h + (size_t)96 * 3648;
    f16* D1  = W2l + (size_t)96 * 3648;        // 3712*96
    f16* D2  = D1  + (size_t)3712 * 96;        // 48*3648
    float* stats = (float*)(D2 + (size_t)48 * 3648);   // 4*16384
    float* s1 = stats;
    float* q1 = stats + 16384;
    float* s3 = stats + 32768;
    float* q3 = stats + 49152;
    float* h2 = stats + 4 * 16384;             // 16384*96 f32
    f16* sigb = (f16*)(h2 + (size_t)16384 * 96);   // 16384*96
    f16* Xh   = (f16*)h2;                      // 8192*768 f16 (aliases h2+sigb+pad)
    float* H1 = (float*)((char*)h2 + 12582912);    // 16384*3600 f32

    hipMemsetAsync(stats, 0, (size_t)4 * 16384 * 4, stream);
    hipMemsetAsync(out, 0, (size_t)16384 * 48 * 4, stream);

    prep_w<<<2048, 256, 0, stream>>>(w1, w2, dw1, dw2, B2, W2h, W2l, D1, D2);

    // conv1 in two M-halves (Xh aliases h2/sigb, dead until conv2)
    prep_xh<<<1536, 256, 0, stream>>>(x, Xh);
    gemm1_async<<<dim3(64, 29), 256, 0, stream>>>(Xh, B2, H1, b1, s1, q1, 0);
    prep_xh<<<1536, 256, 0, stream>>>(x + (size_t)8192 * 720, Xh);
    gemm1_async<<<dim3(64, 29), 256, 0, stream>>>(Xh, B2, H1, b1, s1, q1, 8192);

    // h2 zero AFTER Xh is dead (aliased)
    hipMemsetAsync(h2, 0, (size_t)16384 * 96 * 4, stream);

    // conv2 (3-term split, LN+ELU fused, split-K x4) -> h2 partials (scaled)
    conv2_pk<<<dim3(128, 4), 256, 0, stream>>>(H1, W2h, W2l, s1, q1, nw1, nb1, h2);

    // extraction -> sig
    extract<<<384, 256, 0, stream>>>(h2, b2, fcw, fcb, sigb);

    // deconv path: stats (split-N x2), then fused recompute+LN+ELU+deconv2 (split-K x4)
    deconv1_stats<<<dim3(256, 2), 256, 0, stream>>>(sigb, D1, db1, s3, q3);
    fused_deconv<<<dim3(256, 4), 256, 0, stream>>>(sigb, D1, D2, s3, q3, nw2, nb2, db1, db2, out);
}